// Round 4
// baseline (756.001 us; speedup 1.0000x reference)
//
#include <hip/hip_runtime.h>

#define B_DIM 64
#define S_DIM 784
#define T_DIM 500
#define N_DIM 1024
#define TP    522
#define KS    21
#define THETA 80
#define NCHUNK 8
#define CH    66
#define LISTCAP 128
#define NSPIKE_THREADS (B_DIM * S_DIM * (T_DIM / 4))        // 6,272,000
#define NFILL4 ((B_DIM * N_DIM * TP) / 4)                   // 8,552,448

// ---- K1: wt9[s][n] = w ? 9*(w-1) : 63; row s=784 all-63 (dump target for list
//          padding and w=0). Also zero the per-(b,t) list counters.
__global__ void k_prep(const int* __restrict__ w, unsigned char* __restrict__ wt9,
                       unsigned* __restrict__ gcnt) {
  unsigned idx = blockIdx.x * 256 + threadIdx.x;
  if (idx < (S_DIM + 1) * N_DIM) {
    unsigned s = idx >> 10, n = idx & 1023;
    unsigned char v = 63;
    if (s < S_DIM) {
      int wv = w[n * S_DIM + s];
      v = wv ? (unsigned char)(9 * (wv - 1)) : (unsigned char)63;
    }
    wt9[idx] = v;
  }
  if (idx < B_DIM * T_DIM) gcnt[idx] = 0;
}

// ---- K2: build per-(b,t) spike lists (float4 reads) + zero-fill d_out (fused;
//          both are pure bandwidth, saves a dispatch).
__global__ void k_listsfill(const float4* __restrict__ x4, unsigned* __restrict__ gcnt,
                            unsigned short* __restrict__ glist, int4* __restrict__ out4) {
  unsigned idx = blockIdx.x * 256 + threadIdx.x;
  if (idx < NSPIKE_THREADS) {
    float4 v = x4[idx];
    if (!(v.x == 0.0f && v.y == 0.0f && v.z == 0.0f && v.w == 0.0f)) {
      unsigned tq = idx % (T_DIM / 4);
      unsigned bs = idx / (T_DIM / 4);       // b*S + s
      unsigned s = bs % S_DIM;
      unsigned b = bs / S_DIM;
      unsigned cell = b * T_DIM + tq * 4;
      float f[4] = {v.x, v.y, v.z, v.w};
      #pragma unroll
      for (int k = 0; k < 4; ++k) {
        if (f[k] != 0.0f) {
          unsigned pos = atomicAdd(&gcnt[cell + k], 1u);
          if (pos < LISTCAP) glist[(cell + k) * LISTCAP + pos] = (unsigned short)s;
        }
      }
    }
  }
  if (idx < NFILL4) out4[idx] = make_int4(0, 0, 0, 0);
}

// ---- K3: barrier-free fused sparse conv + argmax (R2 structure). One block =
//          (b, time-chunk); one thread = one neuron; 22-deep shifting register
//          ring; 8 spikes per ds_read_b128 (u16 entries, padded x8 to dump row).
__global__ void __launch_bounds__(1024, 8)
k_main(const unsigned char* __restrict__ wt9,
       const unsigned* __restrict__ gcnt,
       const unsigned short* __restrict__ glist,
       unsigned* __restrict__ red) {
  __shared__ unsigned short s_list[87][LISTCAP];
  __shared__ int s_cnt[87];                  // counts rounded up to multiple of 8
  __shared__ unsigned smax[CH];

  const int tid = threadIdx.x;
  const int b = blockIdx.y;
  const int lo = blockIdx.x * CH;
  const int hi = min(TP - 1, lo + CH - 1);
  const int t0 = max(0, lo - KS);
  const int n_emit = hi - lo + 1;
  const int nt_in = min(hi, T_DIM - 1) - t0 + 1;

  // ---- prologue: stage lists + padded counts + smax
  const unsigned cell0 = (unsigned)b * T_DIM + (unsigned)t0;
  for (int i = tid; i < nt_in; i += 1024) {
    int c = min((int)gcnt[cell0 + i], LISTCAP);
    s_cnt[i] = (c + 7) & ~7;
  }
  {
    const unsigned* src = (const unsigned*)(glist + (size_t)cell0 * LISTCAP);
    unsigned* dst = (unsigned*)&s_list[0][0];
    const int nw = nt_in * (LISTCAP / 2);
    for (int i = tid; i < nw; i += 1024) dst[i] = src[i];
  }
  for (int i = tid; i < n_emit; i += 1024) smax[i] = 0u;
  __syncthreads();
  // pad each list tail [cnt, cnt8) with the dump entry s=784 (all-63 row)
  if (tid < nt_in) {
    int c = min((int)gcnt[cell0 + tid], LISTCAP);
    int c8 = (c + 7) & ~7;
    for (int j = c; j < c8; ++j) s_list[tid][j] = (unsigned short)S_DIM;
  }
  __syncthreads();

  int ring[KS + 1];
  #pragma unroll
  for (int i = 0; i <= KS; ++i) ring[i] = 0;

  const unsigned invn = (unsigned)(1023 - tid);

  for (int t = t0; t <= hi; ++t) {
    // per-t argmax: wave butterfly + one LDS atomicMax per wave (no barrier)
    if (t >= lo) {
      unsigned key = ((unsigned)ring[0] << 10) | invn;
      #pragma unroll
      for (int off = 32; off > 0; off >>= 1) {
        unsigned o = __shfl_xor(key, off, 64);
        key = key > o ? key : o;
      }
      if ((tid & 63) == 0) atomicMax(&smax[t - lo], key);
    }

    if (t < T_DIM) {
      const int li = t - t0;
      const int cnt8 = __builtin_amdgcn_readfirstlane(s_cnt[li]);
      const uint4* lp4 = (const uint4*)&s_list[li][0];
      unsigned long long c0 = 0, c1 = 0, c2 = 0, c3 = 0;
      for (int i = 0; i < cnt8; i += 8) {
        uint4 e = lp4[i >> 3];                 // 8 u16 spike indices, broadcast
        unsigned a0 = ((e.x << 10) & 0x000FFC00u) + tid;
        unsigned a1 = ((e.x >> 6)  & 0x000FFC00u) + tid;
        unsigned a2 = ((e.y << 10) & 0x000FFC00u) + tid;
        unsigned a3 = ((e.y >> 6)  & 0x000FFC00u) + tid;
        unsigned a4 = ((e.z << 10) & 0x000FFC00u) + tid;
        unsigned a5 = ((e.z >> 6)  & 0x000FFC00u) + tid;
        unsigned a6 = ((e.w << 10) & 0x000FFC00u) + tid;
        unsigned a7 = ((e.w >> 6)  & 0x000FFC00u) + tid;
        c0 += 1ull << wt9[a0];
        c1 += 1ull << wt9[a1];
        c2 += 1ull << wt9[a2];
        c3 += 1ull << wt9[a3];
        c0 += 1ull << wt9[a4];
        c1 += 1ull << wt9[a5];
        c2 += 1ull << wt9[a6];
        c3 += 1ull << wt9[a7];
      }
      const unsigned long long c = (c0 + c1) + (c2 + c3);  // bit63 = w0/pad garbage

      const int c1_ = (int)(c & 511), c2_ = (int)((c >> 9) & 511),
                c3_ = (int)((c >> 18) & 511), c4_ = (int)((c >> 27) & 511),
                c5_ = (int)((c >> 36) & 511), c6_ = (int)((c >> 45) & 511),
                c7_ = (int)((c >> 54) & 511);
      // response application as running-delta adds (verified exact, R2)
      const int S7 = c7_, S6 = S7 + c6_, S5 = S6 + c5_, S4 = S5 + c4_,
                S3 = S4 + c3_, S2 = S3 + c2_, S1 = S2 + c1_;
      const int O1 = c1_, O3 = O1 + c3_, O5 = O3 + c5_, O7 = O5 + c7_;
      const int E2 = c2_, E4 = E2 + c4_, E6 = E4 + c6_;
      const int O31 = O3 - O1, O51 = O5 - O1, O71 = O7 - O1,
                O73 = O7 - O3, O75 = O7 - O5;
      const int E62 = E6 - E2, E64 = E6 - E4;
      int acc = S1;        ring[1]  += acc;
      acc += S2;           ring[2]  += acc;
      acc += S3 - O1;      ring[3]  += acc;
      acc += S4 - E2;      ring[4]  += acc;
      acc += S5 - O31;     ring[5]  += acc;
      acc += S6 - E4;      ring[6]  += acc;
      acc += S7 - O51;     ring[7]  += acc;
      acc -= E62;          ring[8]  += acc;
      acc -= O71;          ring[9]  += acc;
      acc -= E62;          ring[10] += acc;
      acc -= O73;          ring[11] += acc;
      acc -= E62;          ring[12] += acc;
      acc -= O73;          ring[13] += acc;
      acc -= E64;          ring[14] += acc;
      acc -= O73;          ring[15] += acc;
      acc -= E64;          ring[16] += acc;
      acc -= O75;          ring[17] += acc;
      acc -= E64;          ring[18] += acc;
      acc -= O75;          ring[19] += acc;
                           ring[20] += acc;
      acc -= O75;          ring[21] += acc;
    }

    #pragma unroll
    for (int i = 0; i < KS; ++i) ring[i] = ring[i + 1];
    ring[KS] = 0;
  }

  __syncthreads();
  for (int i = tid; i < n_emit; i += 1024)
    red[(unsigned)b * TP + (unsigned)(lo + i)] = smax[i];
}

// ---- K4: winner-take-all dep scan; 6-wide load batching
__global__ void k_scan(const unsigned* __restrict__ red, int* __restrict__ out) {
  int b = threadIdx.x;
  if (b >= B_DIM) return;
  int dep = 0;
  for (int base = 0; base < TP; base += 6) {   // 522 = 87*6
    unsigned buf[6];
    #pragma unroll
    for (int k = 0; k < 6; ++k) buf[k] = red[b * TP + base + k];
    #pragma unroll
    for (int k = 0; k < 6; ++k) {
      unsigned key = buf[k];
      int val = (int)(key >> 10);
      bool cond = (val > THETA) && (dep == 0);
      if (cond) {
        int idx = 1023 - (int)(key & 1023);
        out[(b * N_DIM + idx) * TP + base + k] = 1;
        dep = 22;  // FODEP+1
      }
      dep = max(0, dep - 1);
    }
  }
}

extern "C" void kernel_launch(void* const* d_in, const int* in_sizes, int n_in,
                              void* d_out, int out_size, void* d_ws, size_t ws_size,
                              hipStream_t stream) {
  const float* x = (const float*)d_in[0];
  const int* wgt = (const int*)d_in[1];
  int* out = (int*)d_out;

  // workspace layout (total ~9.26 MB)
  unsigned char* wt9    = (unsigned char*)d_ws;                           // 803,840 B
  unsigned* gcnt        = (unsigned*)((char*)d_ws + 803840);              // 128,000 B
  unsigned short* glist = (unsigned short*)((char*)d_ws + 931840);        // 8,192,000 B
  unsigned* red         = (unsigned*)((char*)d_ws + 9123840);             // 133,632 B

  k_prep<<<((S_DIM + 1) * N_DIM + 255) / 256, 256, 0, stream>>>(wgt, wt9, gcnt);
  k_listsfill<<<(NFILL4 + 255) / 256, 256, 0, stream>>>(
      (const float4*)x, gcnt, glist, (int4*)out);
  k_main<<<dim3(NCHUNK, B_DIM), 1024, 0, stream>>>(wt9, gcnt, glist, red);
  k_scan<<<1, 64, 0, stream>>>(red, out);
}

// Round 5
// 714.481 us; speedup vs baseline: 1.0581x; 1.0581x over previous
//
#include <hip/hip_runtime.h>

#define B_DIM 64
#define S_DIM 784
#define T_DIM 500
#define N_DIM 1024
#define TP    522
#define KS    21
#define THETA 80
#define NCHUNK 8
#define CH    66
#define LISTCAP 128
#define NSPIKE_THREADS (B_DIM * S_DIM * (T_DIM / 4))        // 6,272,000
#define NFILL4 ((B_DIM * N_DIM * TP) / 4)                   // 8,552,448

// ---- K1: wt9[s][n] = w ? 9*(w-1) : 63 (shift code). Zero per-(b,t) counters.
__global__ void k_prep(const int* __restrict__ w, unsigned char* __restrict__ wt9,
                       unsigned* __restrict__ gcnt) {
  unsigned idx = blockIdx.x * 256 + threadIdx.x;
  if (idx < S_DIM * N_DIM) {
    unsigned s = idx >> 10, n = idx & 1023;
    int wv = w[n * S_DIM + s];
    wt9[idx] = wv ? (unsigned char)(9 * (wv - 1)) : (unsigned char)63;
  }
  if (idx < B_DIM * T_DIM) gcnt[idx] = 0;
}

// ---- K2: build per-(b,t) spike lists as u32 = (s<<10) (pre-shifted row offsets),
//          fused with d_out zero-fill (both pure bandwidth).
__global__ void k_listsfill(const float4* __restrict__ x4, unsigned* __restrict__ gcnt,
                            unsigned* __restrict__ glist32, int4* __restrict__ out4) {
  unsigned idx = blockIdx.x * 256 + threadIdx.x;
  if (idx < NSPIKE_THREADS) {
    float4 v = x4[idx];
    if (!(v.x == 0.0f && v.y == 0.0f && v.z == 0.0f && v.w == 0.0f)) {
      unsigned tq = idx % (T_DIM / 4);
      unsigned bs = idx / (T_DIM / 4);       // b*S + s
      unsigned s = bs % S_DIM;
      unsigned b = bs / S_DIM;
      unsigned cell = b * T_DIM + tq * 4;
      float f[4] = {v.x, v.y, v.z, v.w};
      #pragma unroll
      for (int k = 0; k < 4; ++k) {
        if (f[k] != 0.0f) {
          unsigned pos = atomicAdd(&gcnt[cell + k], 1u);
          if (pos < LISTCAP) glist32[(cell + k) * LISTCAP + pos] = (s << 10);
        }
      }
    }
  }
  if (idx < NFILL4) out4[idx] = make_int4(0, 0, 0, 0);
}

// ---- K3: fused sparse conv + argmax. Lists read via wave-uniform pointers from
//          global (SMEM/s_load path); table-row base = SGPR pair, tid = VGPR
//          offset -> only 3 VALU per spike (lshl_b64 + 64-bit add).
__global__ void __launch_bounds__(1024, 8)
k_main(const unsigned char* __restrict__ wt9,
       const unsigned* __restrict__ gcnt,
       const unsigned* __restrict__ glist32,
       unsigned* __restrict__ red) {
  __shared__ unsigned smax[CH];

  const int tid = threadIdx.x;
  const int b = blockIdx.y;
  const int lo = blockIdx.x * CH;
  const int hi = min(TP - 1, lo + CH - 1);
  const int t0 = max(0, lo - KS);
  const int n_emit = hi - lo + 1;

  for (int i = tid; i < n_emit; i += 1024) smax[i] = 0u;
  __syncthreads();

  int ring[KS + 1];
  #pragma unroll
  for (int i = 0; i <= KS; ++i) ring[i] = 0;

  const unsigned invn = (unsigned)(1023 - tid);
  const unsigned cell0 = (unsigned)b * T_DIM + (unsigned)t0;

  // prefetch first count (uniform -> s_load)
  int cnt_next = (int)gcnt[cell0];

  for (int t = t0; t <= hi; ++t) {
    const int cnt = min(cnt_next, LISTCAP);
    // prefetch next count early so the s_load latency hides under this iter
    if (t + 1 <= hi && t + 1 < T_DIM) cnt_next = (int)gcnt[cell0 + (t + 1 - t0)];

    // per-t argmax: wave butterfly + one LDS atomicMax per wave (no barrier)
    if (t >= lo) {
      unsigned key = ((unsigned)ring[0] << 10) | invn;
      #pragma unroll
      for (int off = 32; off > 0; off >>= 1) {
        unsigned o = __shfl_xor(key, off, 64);
        key = key > o ? key : o;
      }
      if ((tid & 63) == 0) atomicMax(&smax[t - lo], key);
    }

    if (t < T_DIM) {
      const unsigned* gl = glist32 + (size_t)(cell0 + (unsigned)(t - t0)) * LISTCAP;
      unsigned long long c0 = 0, c1 = 0, c2 = 0, c3 = 0;
      int i = 0;
      for (; i + 3 < cnt; i += 4) {
        unsigned e0 = gl[i], e1 = gl[i + 1], e2 = gl[i + 2], e3 = gl[i + 3];
        const unsigned char* r0 = wt9 + e0;   // uniform pointers -> SGPR base
        const unsigned char* r1 = wt9 + e1;
        const unsigned char* r2 = wt9 + e2;
        const unsigned char* r3 = wt9 + e3;
        c0 += 1ull << r0[tid];
        c1 += 1ull << r1[tid];
        c2 += 1ull << r2[tid];
        c3 += 1ull << r3[tid];
      }
      for (; i < cnt; ++i) {
        const unsigned char* r = wt9 + gl[i];
        c0 += 1ull << r[tid];
      }
      const unsigned long long c = (c0 + c1) + (c2 + c3);  // bit63 = w0 garbage

      const int c1_ = (int)(c & 511), c2_ = (int)((c >> 9) & 511),
                c3_ = (int)((c >> 18) & 511), c4_ = (int)((c >> 27) & 511),
                c5_ = (int)((c >> 36) & 511), c6_ = (int)((c >> 45) & 511),
                c7_ = (int)((c >> 54) & 511);
      // response application as running-delta adds (verified exact, R2)
      const int S7 = c7_, S6 = S7 + c6_, S5 = S6 + c5_, S4 = S5 + c4_,
                S3 = S4 + c3_, S2 = S3 + c2_, S1 = S2 + c1_;
      const int O1 = c1_, O3 = O1 + c3_, O5 = O3 + c5_, O7 = O5 + c7_;
      const int E2 = c2_, E4 = E2 + c4_, E6 = E4 + c6_;
      const int O31 = O3 - O1, O51 = O5 - O1, O71 = O7 - O1,
                O73 = O7 - O3, O75 = O7 - O5;
      const int E62 = E6 - E2, E64 = E6 - E4;
      int acc = S1;        ring[1]  += acc;
      acc += S2;           ring[2]  += acc;
      acc += S3 - O1;      ring[3]  += acc;
      acc += S4 - E2;      ring[4]  += acc;
      acc += S5 - O31;     ring[5]  += acc;
      acc += S6 - E4;      ring[6]  += acc;
      acc += S7 - O51;     ring[7]  += acc;
      acc -= E62;          ring[8]  += acc;
      acc -= O71;          ring[9]  += acc;
      acc -= E62;          ring[10] += acc;
      acc -= O73;          ring[11] += acc;
      acc -= E62;          ring[12] += acc;
      acc -= O73;          ring[13] += acc;
      acc -= E64;          ring[14] += acc;
      acc -= O73;          ring[15] += acc;
      acc -= E64;          ring[16] += acc;
      acc -= O75;          ring[17] += acc;
      acc -= E64;          ring[18] += acc;
      acc -= O75;          ring[19] += acc;
                           ring[20] += acc;
      acc -= O75;          ring[21] += acc;
    }

    #pragma unroll
    for (int i = 0; i < KS; ++i) ring[i] = ring[i + 1];
    ring[KS] = 0;
  }

  __syncthreads();
  for (int i = tid; i < n_emit; i += 1024)
    red[(unsigned)b * TP + (unsigned)(lo + i)] = smax[i];
}

// ---- K4: winner-take-all dep scan; 6-wide load batching
__global__ void k_scan(const unsigned* __restrict__ red, int* __restrict__ out) {
  int b = threadIdx.x;
  if (b >= B_DIM) return;
  int dep = 0;
  for (int base = 0; base < TP; base += 6) {   // 522 = 87*6
    unsigned buf[6];
    #pragma unroll
    for (int k = 0; k < 6; ++k) buf[k] = red[b * TP + base + k];
    #pragma unroll
    for (int k = 0; k < 6; ++k) {
      unsigned key = buf[k];
      int val = (int)(key >> 10);
      bool cond = (val > THETA) && (dep == 0);
      if (cond) {
        int idx = 1023 - (int)(key & 1023);
        out[(b * N_DIM + idx) * TP + base + k] = 1;
        dep = 22;  // FODEP+1
      }
      dep = max(0, dep - 1);
    }
  }
}

extern "C" void kernel_launch(void* const* d_in, const int* in_sizes, int n_in,
                              void* d_out, int out_size, void* d_ws, size_t ws_size,
                              hipStream_t stream) {
  const float* x = (const float*)d_in[0];
  const int* wgt = (const int*)d_in[1];
  int* out = (int*)d_out;

  // workspace layout (~17.0 MB)
  unsigned char* wt9 = (unsigned char*)d_ws;                        // 802,816 B
  unsigned* gcnt     = (unsigned*)((char*)d_ws + 802816);           // 128,000 B
  unsigned* glist32  = (unsigned*)((char*)d_ws + 930816);           // 16,384,000 B
  unsigned* red      = (unsigned*)((char*)d_ws + 17314816);         // 133,632 B

  k_prep<<<(S_DIM * N_DIM + 255) / 256, 256, 0, stream>>>(wgt, wt9, gcnt);
  k_listsfill<<<(NFILL4 + 255) / 256, 256, 0, stream>>>(
      (const float4*)x, gcnt, glist32, (int4*)out);
  k_main<<<dim3(NCHUNK, B_DIM), 1024, 0, stream>>>(wt9, gcnt, glist32, red);
  k_scan<<<1, 64, 0, stream>>>(red, out);
}

// Round 7
// 684.491 us; speedup vs baseline: 1.1045x; 1.0438x over previous
//
#include <hip/hip_runtime.h>

#define B_DIM 64
#define S_DIM 784
#define T_DIM 500
#define N_DIM 1024
#define TP    522
#define KS    21
#define THETA 80
#define NCHUNK 8
#define CH    66
#define LISTCAP 128
#define NSPIKE_THREADS (B_DIM * S_DIM * (T_DIM / 4))        // 6,272,000
#define NFILL4 ((B_DIM * N_DIM * TP) / 4)                   // 8,552,448

typedef unsigned uint4v __attribute__((ext_vector_type(4)));

// ---- K1: wt9[s][n] = w ? 9*(w-1) : 63; row s=784 all-63 (dump row for padding).
//          Zero per-(b,t) list counters.
__global__ void k_prep(const int* __restrict__ w, unsigned char* __restrict__ wt9,
                       unsigned* __restrict__ gcnt) {
  unsigned idx = blockIdx.x * 256 + threadIdx.x;
  if (idx < (S_DIM + 1) * N_DIM) {
    unsigned s = idx >> 10, n = idx & 1023;
    unsigned char v = 63;
    if (s < S_DIM) {
      int wv = w[n * S_DIM + s];
      v = wv ? (unsigned char)(9 * (wv - 1)) : (unsigned char)63;
    }
    wt9[idx] = v;
  }
  if (idx < B_DIM * T_DIM) gcnt[idx] = 0;
}

// ---- K2: build per-(b,t) spike lists (u16 s, STRIDED slot map: pos j ->
//          (j&3)*32 + (j>>2), so k_main's 4 ds_read_u16 per iter are 64B apart
//          -> no SLP merge into VALU unpacking) + zero-fill d_out (fused).
__global__ void k_listsfill(const uint4v* __restrict__ x4, unsigned* __restrict__ gcnt,
                            unsigned short* __restrict__ glist, uint4v* __restrict__ out4) {
  unsigned idx = blockIdx.x * 256 + threadIdx.x;
  if (idx < NSPIKE_THREADS) {
    uint4v v = __builtin_nontemporal_load(&x4[idx]);
    if (v.x | v.y | v.z | v.w) {
      unsigned tq = idx % (T_DIM / 4);
      unsigned bs = idx / (T_DIM / 4);       // b*S + s
      unsigned s = bs % S_DIM;
      unsigned b = bs / S_DIM;
      unsigned cell = b * T_DIM + tq * 4;
      #pragma unroll
      for (int k = 0; k < 4; ++k) {
        if (v[k]) {
          unsigned pos = atomicAdd(&gcnt[cell + k], 1u);
          if (pos < LISTCAP)
            glist[(cell + k) * LISTCAP + ((pos & 3) * 32 + (pos >> 2))] = (unsigned short)s;
        }
      }
    }
  }
  if (idx < NFILL4) {
    uint4v z = {0, 0, 0, 0};
    __builtin_nontemporal_store(z, &out4[idx]);
  }
}

// ---- K3: fused sparse conv + argmax (R2 structure). One block = (b, t-chunk);
//          one thread = one neuron; 22-deep shifting ring; per spike:
//          ds_read_u16 + v_lshl_add_u32 + global_load_ubyte + (lshl_b64 + add64).
//          NOTE: c += 1ull << w must stay plain C — v_lshl_add_u64's shift
//          operand is S1[2:0] (3 bits only); R6's inline asm silently aliased
//          all class counters mod 8.
__global__ void __launch_bounds__(1024, 8)
k_main(const unsigned char* __restrict__ wt9,
       const unsigned* __restrict__ gcnt,
       const unsigned short* __restrict__ glist,
       unsigned* __restrict__ red) {
  __shared__ unsigned short s_list[87][LISTCAP];
  __shared__ int s_cnt[87];                  // counts rounded up to multiple of 4
  __shared__ unsigned smax[CH];

  const int tid = threadIdx.x;
  const int b = blockIdx.y;
  const int lo = blockIdx.x * CH;
  const int hi = min(TP - 1, lo + CH - 1);
  const int t0 = max(0, lo - KS);
  const int n_emit = hi - lo + 1;
  const int nt_in = min(hi, T_DIM - 1) - t0 + 1;

  // ---- prologue: stage lists + padded counts + smax
  const unsigned cell0 = (unsigned)b * T_DIM + (unsigned)t0;
  for (int i = tid; i < nt_in; i += 1024) {
    int c = min((int)gcnt[cell0 + i], LISTCAP);
    s_cnt[i] = (c + 3) & ~3;
  }
  {
    const unsigned* src = (const unsigned*)(glist + (size_t)cell0 * LISTCAP);
    unsigned* dst = (unsigned*)&s_list[0][0];
    const int nw = nt_in * (LISTCAP / 2);
    for (int i = tid; i < nw; i += 1024) dst[i] = src[i];
  }
  for (int i = tid; i < n_emit; i += 1024) smax[i] = 0u;
  __syncthreads();
  // pad strided tail slots [cnt, cnt4) with dump entry s=784 (all-63 row)
  if (tid < nt_in) {
    int c = min((int)gcnt[cell0 + tid], LISTCAP);
    int c4 = (c + 3) & ~3;
    for (int j = c; j < c4; ++j)
      s_list[tid][(j & 3) * 32 + (j >> 2)] = (unsigned short)S_DIM;
  }
  __syncthreads();

  int ring[KS + 1];
  #pragma unroll
  for (int i = 0; i <= KS; ++i) ring[i] = 0;

  const unsigned invn = (unsigned)(1023 - tid);

  for (int t = t0; t <= hi; ++t) {
    // per-t argmax: wave butterfly + one LDS atomicMax per wave (no barrier)
    if (t >= lo) {
      unsigned key = ((unsigned)ring[0] << 10) | invn;
      #pragma unroll
      for (int off = 32; off > 0; off >>= 1) {
        unsigned o = __shfl_xor(key, off, 64);
        key = key > o ? key : o;
      }
      if ((tid & 63) == 0) atomicMax(&smax[t - lo], key);
    }

    if (t < T_DIM) {
      const int li = t - t0;
      const int nq = __builtin_amdgcn_readfirstlane(s_cnt[li]) >> 2;
      const unsigned short* lp = &s_list[li][0];
      unsigned long long c0 = 0, c1 = 0, c2 = 0, c3 = 0;
      for (int q = 0; q < nq; ++q) {
        unsigned e0 = lp[q];        // strided: 4 reads 64B apart, broadcast
        unsigned e1 = lp[q + 32];
        unsigned e2 = lp[q + 64];
        unsigned e3 = lp[q + 96];
        unsigned w0 = wt9[(e0 << 10) + tid];
        unsigned w1 = wt9[(e1 << 10) + tid];
        unsigned w2 = wt9[(e2 << 10) + tid];
        unsigned w3 = wt9[(e3 << 10) + tid];
        c0 += 1ull << w0;
        c1 += 1ull << w1;
        c2 += 1ull << w2;
        c3 += 1ull << w3;
      }
      const unsigned long long c = (c0 + c1) + (c2 + c3);  // bit63 = w0/pad garbage

      const int c1_ = (int)(c & 511), c2_ = (int)((c >> 9) & 511),
                c3_ = (int)((c >> 18) & 511), c4_ = (int)((c >> 27) & 511),
                c5_ = (int)((c >> 36) & 511), c6_ = (int)((c >> 45) & 511),
                c7_ = (int)((c >> 54) & 511);
      // response application as running-delta adds (verified exact, R2)
      const int S7 = c7_, S6 = S7 + c6_, S5 = S6 + c5_, S4 = S5 + c4_,
                S3 = S4 + c3_, S2 = S3 + c2_, S1 = S2 + c1_;
      const int O1 = c1_, O3 = O1 + c3_, O5 = O3 + c5_, O7 = O5 + c7_;
      const int E2 = c2_, E4 = E2 + c4_, E6 = E4 + c6_;
      const int O31 = O3 - O1, O51 = O5 - O1, O71 = O7 - O1,
                O73 = O7 - O3, O75 = O7 - O5;
      const int E62 = E6 - E2, E64 = E6 - E4;
      int acc = S1;        ring[1]  += acc;
      acc += S2;           ring[2]  += acc;
      acc += S3 - O1;      ring[3]  += acc;
      acc += S4 - E2;      ring[4]  += acc;
      acc += S5 - O31;     ring[5]  += acc;
      acc += S6 - E4;      ring[6]  += acc;
      acc += S7 - O51;     ring[7]  += acc;
      acc -= E62;          ring[8]  += acc;
      acc -= O71;          ring[9]  += acc;
      acc -= E62;          ring[10] += acc;
      acc -= O73;          ring[11] += acc;
      acc -= E62;          ring[12] += acc;
      acc -= O73;          ring[13] += acc;
      acc -= E64;          ring[14] += acc;
      acc -= O73;          ring[15] += acc;
      acc -= E64;          ring[16] += acc;
      acc -= O75;          ring[17] += acc;
      acc -= E64;          ring[18] += acc;
      acc -= O75;          ring[19] += acc;
                           ring[20] += acc;
      acc -= O75;          ring[21] += acc;
    }

    #pragma unroll
    for (int i = 0; i < KS; ++i) ring[i] = ring[i + 1];
    ring[KS] = 0;
  }

  __syncthreads();
  for (int i = tid; i < n_emit; i += 1024)
    red[(unsigned)b * TP + (unsigned)(lo + i)] = smax[i];
}

// ---- K4: winner-take-all dep scan; one block per b, keys staged in LDS so the
//          serial 522-step chain runs LDS-speed (64 blocks in parallel)
__global__ void k_scan(const unsigned* __restrict__ red, int* __restrict__ out) {
  __shared__ unsigned sk[TP];
  const int b = blockIdx.x;
  for (int i = threadIdx.x; i < TP; i += 64) sk[i] = red[b * TP + i];
  __syncthreads();
  if (threadIdx.x == 0) {
    int dep = 0;
    for (int base = 0; base < TP; base += 6) {   // 522 = 87*6
      unsigned buf[6];
      #pragma unroll
      for (int k = 0; k < 6; ++k) buf[k] = sk[base + k];
      #pragma unroll
      for (int k = 0; k < 6; ++k) {
        unsigned key = buf[k];
        bool cond = ((key >> 10) > THETA) && (dep == 0);
        if (cond) {
          out[(b * N_DIM + (1023 - (int)(key & 1023))) * TP + base + k] = 1;
          dep = 22;  // FODEP+1
        }
        dep = max(0, dep - 1);
      }
    }
  }
}

extern "C" void kernel_launch(void* const* d_in, const int* in_sizes, int n_in,
                              void* d_out, int out_size, void* d_ws, size_t ws_size,
                              hipStream_t stream) {
  const float* x = (const float*)d_in[0];
  const int* wgt = (const int*)d_in[1];
  int* out = (int*)d_out;

  // workspace layout (~9.26 MB)
  unsigned char* wt9    = (unsigned char*)d_ws;                        // 803,840 B
  unsigned* gcnt        = (unsigned*)((char*)d_ws + 803840);           // 128,000 B
  unsigned short* glist = (unsigned short*)((char*)d_ws + 931840);     // 8,192,000 B
  unsigned* red         = (unsigned*)((char*)d_ws + 9123840);          // 133,632 B

  k_prep<<<((S_DIM + 1) * N_DIM + 255) / 256, 256, 0, stream>>>(wgt, wt9, gcnt);
  k_listsfill<<<(NFILL4 + 255) / 256, 256, 0, stream>>>(
      (const uint4v*)x, gcnt, glist, (uint4v*)out);
  k_main<<<dim3(NCHUNK, B_DIM), 1024, 0, stream>>>(wt9, gcnt, glist, red);
  k_scan<<<B_DIM, 64, 0, stream>>>(red, out);
}